// Round 6
// baseline (8166.828 us; speedup 1.0000x reference)
//
#include <hip/hip_runtime.h>
#include <math.h>

// FWI forward: 10 shots, 1000 steps, padded grid 130x160 (NBC=30).
// R6: 4-wide x 6-tall tile per thread; BOTH time levels (p1,p0) in registers
// (two generations, static-swapped via 2x-unrolled time loop). LDS holds only
// the haloed p1 mirror (for neighbor exchange) + wavelet. P0s (R5's bank-
// conflict source, stride 160 = 0 mod 32) is gone. Per thread-step LDS:
// 4 b128 z-halo + 12 b64 x-halo reads + 6 b128 writes = 256 B (R4: 1680 B).
// 880 active threads (block 896 = 14 waves, 3.5/SIMD) -> VALU-bound floor.

#define SROW 168                 // Ps row stride; col = x + 4; 168 % 32 = 8
#define PSZ (136 * SROW)         // rows -2..133 stored -> group-21 halo in-bounds
#define RH 6                     // rows per thread
#define NGRP 22                  // 22 groups x 6 = 132 >= 130 rows
#define DTf 0.0008f
#define C2f 1.3333333333333333f  // 4/3
#define C3f (-0.08333333333333333f) // -1/12

#define LD4(arr, i) (*reinterpret_cast<const float4*>(&(arr)[i]))
#define LD2(arr, i) (*reinterpret_cast<const float2*>(&(arr)[i]))
#define ST4(arr, i, v) (*reinterpret_cast<float4*>(&(arr)[i]) = (v))

// ---------- setup 1: velmin reduction, Ricker wavelet, source amplitudes ----------
__global__ __launch_bounds__(1024) void fwi_setup1(const float* __restrict__ v,
                                                   float* __restrict__ ws) {
    int tid = threadIdx.x;
    float m = 3.402823466e38f;
    for (int i = tid; i < 7000; i += 1024) m = fminf(m, v[i]);
    #pragma unroll
    for (int off = 32; off > 0; off >>= 1) m = fminf(m, __shfl_down(m, off, 64));
    __shared__ float red[16];
    if ((tid & 63) == 0) red[tid >> 6] = m;
    __syncthreads();
    if (tid == 0) {
        float mm = red[0];
        for (int i = 1; i < 16; ++i) mm = fminf(mm, red[i]);
        ws[1010] = mm * 1000.0f + 3000.0f;   // denormalized velmin
    }
    // Ricker wavelet: nw=111, nc=55, f*dt*pi = 0.06283185307179587
    if (tid < 1000) {
        float w = 0.0f;
        if (tid < 111) {
            float a = (float)(55 - tid) * 0.06283185307179587f;
            float b = a * a;
            w = (1.0f - 2.0f * b) * expf(-b);
        }
        ws[tid] = w;
    }
    // src_amp[l] = ((v[1][11l]*1000+3000)*DT)^2
    if (tid >= 1000 && tid < 1010) {
        int l = tid - 1000;
        float vd = v[100 + 11 * l] * 1000.0f + 3000.0f;
        float bdt = vd * DTf;
        ws[tid] = bdt * bdt;
    }
}

// ---------- setup 2: per-cell constants, SoA: AL, T1, T2 ----------
__global__ __launch_bounds__(256) void fwi_setup2(const float* __restrict__ v,
                                                  const float* __restrict__ ws,
                                                  float* __restrict__ AL,
                                                  float* __restrict__ T1,
                                                  float* __restrict__ T2) {
    int c = blockIdx.x * 256 + threadIdx.x;
    if (c >= 130 * 160) return;
    float velmin = ws[1010];
    int z = c / 160;
    int x = c - z * 160;
    int iz = min(max(z - 30, 0), 69);
    int ix = min(max(x - 30, 0), 99);
    float vd = v[iz * 100 + ix] * 1000.0f + 3000.0f;
    float tt = vd * DTf / 10.0f;       // v*DT/DX
    float al = tt * tt;                // alpha
    int qx = max(29 - x, x - 130);
    int qz = max(29 - z, z - 100);
    int q = (qx >= 0) ? qx : qz;
    float kdt = 0.0f;
    if (q >= 0) {
        float kap3 = 3.0f * velmin * 16.118095650958319f / 580.0f; // 3*velmin*ln(1e7)/(2*290)
        float r = (float)q * (10.0f / 290.0f);
        kdt = kap3 * (r * r) * DTf;
    }
    AL[c] = al;
    T1[c] = 2.0f - 5.0f * al - kdt;    // temp1 = 2 + 2*C1*alpha - kappa*dt
    T2[c] = 1.0f - kdt;                // temp2 (exact reference rounding)
}

__device__ __forceinline__ float cellq(float l2, float l1, float cc, float r1, float r2,
                                       float u1, float u2, float d1, float d2,
                                       float al, float t1, float t2, float p0) {
    float lap = C2f * ((l1 + r1) + (u1 + d1)) + C3f * ((l2 + r2) + (u2 + d2));
    return t1 * cc - t2 * p0 + al * lap;
}

// One timestep: CUR = p1 generation (registers), OLD = p0 generation; the new
// field overwrites OLD (generation swap handled by alternating macro args).
#define STEP(CUR, OLD, T) do {                                                  \
    const float as = ((T) < 111) ? amp * Wv[(T)] : 0.0f;                        \
    if (act) {                                                                  \
        float4 hu2 = LD4(Ps, pc0 - 2 * SROW);                                   \
        float4 hu1 = LD4(Ps, pc0 - 1 * SROW);                                   \
        float4 hd1 = LD4(Ps, pc0 + RH * SROW);                                  \
        float4 hd2 = LD4(Ps, pc0 + (RH + 1) * SROW);                            \
        _Pragma("unroll")                                                       \
        for (int r = 0; r < RH; ++r) {                                          \
            if (r < zlim) {                                                     \
                const int pc = pc0 + r * SROW;                                  \
                float2 hl = LD2(Ps, pc - 2);                                    \
                float2 hr = LD2(Ps, pc + 4);                                    \
                float4 c  = CUR[r];                                             \
                float4 u1 = (r == 0) ? hu1 : CUR[(r >= 1) ? r - 1 : 0];         \
                float4 u2 = (r == 0) ? hu2 :                                    \
                            ((r == 1) ? hu1 : CUR[(r >= 2) ? r - 2 : 0]);       \
                float4 d1 = (r == RH - 1) ? hd1 : CUR[(r + 1 < RH) ? r + 1 : 0];\
                float4 d2 = (r == RH - 1) ? hd2 :                               \
                            ((r == RH - 2) ? hd1 : CUR[(r + 2 < RH) ? r + 2 : 0]);\
                float4 al = AL4[cb0 + r * 40];                                  \
                float4 t1 = T14[cb0 + r * 40];                                  \
                float4 t2 = T24[cb0 + r * 40];                                  \
                float4 p0 = OLD[r];                                             \
                float4 q;                                                       \
                q.x = cellq(hl.x, hl.y, c.x, c.y, c.z,                          \
                            u1.x, u2.x, d1.x, d2.x, al.x, t1.x, t2.x, p0.x);    \
                q.y = cellq(hl.y, c.x, c.y, c.z, c.w,                           \
                            u1.y, u2.y, d1.y, d2.y, al.y, t1.y, t2.y, p0.y);    \
                q.z = cellq(c.x, c.y, c.z, c.w, hr.x,                           \
                            u1.z, u2.z, d1.z, d2.z, al.z, t1.z, t2.z, p0.z);    \
                q.w = cellq(c.y, c.z, c.w, hr.x, hr.y,                          \
                            u1.w, u2.w, d1.w, d2.w, al.w, t1.w, t2.w, p0.w);    \
                if (r == 1 && isrc) {   /* source at z=31 (g=5,r=1), post-stencil */ \
                    q.x += (ls == 0) ? as : 0.0f;                               \
                    q.y += (ls == 1) ? as : 0.0f;                               \
                    q.z += (ls == 2) ? as : 0.0f;                               \
                    q.w += (ls == 3) ? as : 0.0f;                               \
                }                                                               \
                OLD[r] = q;             /* new gen overwrites old gen */        \
            }                                                                   \
        }                                                                       \
    }                                                                           \
    __syncthreads();                    /* all halo reads of Ps complete */     \
    if (act) {                                                                  \
        _Pragma("unroll")                                                       \
        for (int r = 0; r < RH; ++r)                                            \
            if (r < zlim) ST4(Ps, pc0 + r * SROW, OLD[r]);                      \
    }                                                                           \
    __syncthreads();                    /* new p1 visible */                    \
    if (tid < 100)                      /* receivers: z=31 row, x=30..129 */    \
        out[shot * 100000 + (T) * 100 + tid] = Ps[33 * SROW + 34 + tid];        \
} while (0)

// ---------- main: one block per shot, 1000 steps ----------
__global__ __launch_bounds__(896) void fwi_main(const float4* __restrict__ AL4,
                                                const float4* __restrict__ T14,
                                                const float4* __restrict__ T24,
                                                const float* __restrict__ ws,
                                                float* __restrict__ out) {
    __shared__ float Ps[PSZ];      // p1 mirror, haloed, stride 168 (91,392 B)
    __shared__ float Wv[128];      // Ricker wavelet (nonzero only t < 111)
    const int tid = threadIdx.x;
    const int shot = blockIdx.x;

    for (int i = tid; i < PSZ; i += 896) Ps[i] = 0.0f;
    if (tid < 128) Wv[tid] = (tid < 111) ? ws[tid] : 0.0f;

    const int g  = tid / 40;            // z-group 0..21 active, 22 idle
    const int qx = tid - g * 40;        // x-quad 0..39, cells x0 = 4*qx
    const int z0 = g * RH;
    const bool act = (g < NGRP);
    const float amp = ws[1000 + shot];
    const int xs = 30 + 11 * shot;      // source x (z=31 -> g=5, r=1)
    const bool isrc = act && (g == 5) && (qx == (xs >> 2));
    const int ls = xs & 3;
    const int pc0 = (z0 + 2) * SROW + 4 * qx + 4;  // Ps index of row z0 quad
    const int cb0 = z0 * 40 + qx;                  // coefficient quad index
    const int zlim = 130 - z0;                     // rows r < zlim are valid

    float4 pA[RH], pB[RH];              // two field generations, all in regs
    #pragma unroll
    for (int r = 0; r < RH; ++r) {
        pA[r] = make_float4(0.f, 0.f, 0.f, 0.f);
        pB[r] = make_float4(0.f, 0.f, 0.f, 0.f);
    }
    __syncthreads();

    for (int t = 0; t < 1000; t += 2) {
        STEP(pB, pA, t);       // p1=pB, p0=pA -> new field lands in pA
        STEP(pA, pB, t + 1);   // roles swapped; static register names
    }
}

extern "C" void kernel_launch(void* const* d_in, const int* in_sizes, int n_in,
                              void* d_out, int out_size, void* d_ws, size_t ws_size,
                              hipStream_t stream) {
    const float* v = (const float*)d_in[0];
    float* ws = (float*)d_ws;                          // [0..999] wavelet, [1000..1009] amps, [1010] velmin
    float* AL = (float*)((char*)d_ws + 4096);          // 20800 floats
    float* T1 = (float*)((char*)d_ws + 4096 + 83200);  // 20800 floats
    float* T2 = (float*)((char*)d_ws + 4096 + 166400); // 20800 floats
    float* out = (float*)d_out;

    fwi_setup1<<<1, 1024, 0, stream>>>(v, ws);
    fwi_setup2<<<82, 256, 0, stream>>>(v, ws, AL, T1, T2);
    fwi_main<<<10, 896, 0, stream>>>((const float4*)AL, (const float4*)T1,
                                     (const float4*)T2, ws, out);
}

// Round 7
// 4312.564 us; speedup vs baseline: 1.8937x; 1.8937x over previous
//
#include <hip/hip_runtime.h>
#include <math.h>

// FWI forward: 10 shots, 1000 steps, padded grid 130x160 (NBC=30).
// R7 = R6's both-generations-in-registers design re-fitted to the proven
// 512-thread envelope (block 512 reliably gets ~128 VGPRs; 896 got 64 and
// latency-serialized). 12 z-groups x 40 x-quads = 480 active threads,
// tile 4 wide x 11 tall. Persistent state 2 gens x 11 float4 = 88 regs.
// Coefficients: 2 streams (AL, KD); t1/t2 derived in-kernel (same float ops
// as validated setup2: t1 = 2 - 5*al - kd, t2 = 1 - kd).
// LDS: only haloed p1 mirror (stride 168 == 8 mod 32; no P0s -> no R5-style
// conflicts). Per-thread-step DS: 4 b128 z-halo + 22 b64 x-halo + 11 b128
// writes = 416 B (R4: 1680 B).

#define SROW 168                 // Ps row stride; col = x + 4
#define PSZ (136 * SROW)         // stored rows -2..133 (group-11 halo in-bounds)
#define RH 11                    // rows per thread
#define NGRP 12                  // 12 groups x 11 = 132 >= 130 rows
#define DTf 0.0008f
#define C2f 1.3333333333333333f  // 4/3
#define C3f (-0.08333333333333333f) // -1/12

#define LD4(arr, i) (*reinterpret_cast<const float4*>(&(arr)[i]))
#define LD2(arr, i) (*reinterpret_cast<const float2*>(&(arr)[i]))
#define ST4(arr, i, v) (*reinterpret_cast<float4*>(&(arr)[i]) = (v))

// ---------- setup 1: velmin reduction, Ricker wavelet, source amplitudes ----------
__global__ __launch_bounds__(1024) void fwi_setup1(const float* __restrict__ v,
                                                   float* __restrict__ ws) {
    int tid = threadIdx.x;
    float m = 3.402823466e38f;
    for (int i = tid; i < 7000; i += 1024) m = fminf(m, v[i]);
    #pragma unroll
    for (int off = 32; off > 0; off >>= 1) m = fminf(m, __shfl_down(m, off, 64));
    __shared__ float red[16];
    if ((tid & 63) == 0) red[tid >> 6] = m;
    __syncthreads();
    if (tid == 0) {
        float mm = red[0];
        for (int i = 1; i < 16; ++i) mm = fminf(mm, red[i]);
        ws[1010] = mm * 1000.0f + 3000.0f;   // denormalized velmin
    }
    // Ricker wavelet: nw=111, nc=55, f*dt*pi = 0.06283185307179587
    if (tid < 1000) {
        float w = 0.0f;
        if (tid < 111) {
            float a = (float)(55 - tid) * 0.06283185307179587f;
            float b = a * a;
            w = (1.0f - 2.0f * b) * expf(-b);
        }
        ws[tid] = w;
    }
    // src_amp[l] = ((v[1][11l]*1000+3000)*DT)^2
    if (tid >= 1000 && tid < 1010) {
        int l = tid - 1000;
        float vd = v[100 + 11 * l] * 1000.0f + 3000.0f;
        float bdt = vd * DTf;
        ws[tid] = bdt * bdt;
    }
}

// ---------- setup 2: per-cell constants, SoA: AL (alpha), KD (kappa*dt) ----------
__global__ __launch_bounds__(256) void fwi_setup2(const float* __restrict__ v,
                                                  const float* __restrict__ ws,
                                                  float* __restrict__ AL,
                                                  float* __restrict__ KD) {
    int c = blockIdx.x * 256 + threadIdx.x;
    if (c >= 130 * 160) return;
    float velmin = ws[1010];
    int z = c / 160;
    int x = c - z * 160;
    int iz = min(max(z - 30, 0), 69);
    int ix = min(max(x - 30, 0), 99);
    float vd = v[iz * 100 + ix] * 1000.0f + 3000.0f;
    float tt = vd * DTf / 10.0f;       // v*DT/DX
    float al = tt * tt;                // alpha
    int qx = max(29 - x, x - 130);
    int qz = max(29 - z, z - 100);
    int q = (qx >= 0) ? qx : qz;
    float kdt = 0.0f;
    if (q >= 0) {
        float kap3 = 3.0f * velmin * 16.118095650958319f / 580.0f; // 3*velmin*ln(1e7)/(2*290)
        float r = (float)q * (10.0f / 290.0f);
        kdt = kap3 * (r * r) * DTf;
    }
    AL[c] = al;
    KD[c] = kdt;                       // t1 = 2 - 5*al - kd; t2 = 1 - kd (in main)
}

__device__ __forceinline__ float cellq(float l2, float l1, float cc, float r1, float r2,
                                       float u1, float u2, float d1, float d2,
                                       float al, float kd, float p0) {
    float lap = C2f * ((l1 + r1) + (u1 + d1)) + C3f * ((l2 + r2) + (u2 + d2));
    float t1  = 2.0f - 5.0f * al - kd;   // same op order as validated setup2
    float t2  = 1.0f - kd;
    return t1 * cc - t2 * p0 + al * lap;
}

// One timestep. CUR = current field (p1) registers; OLD = previous field (p0)
// registers; new field overwrites OLD (p0 is pointwise -> owner-private).
#define STEP(CUR, OLD, T) do {                                                  \
    const float as = ((T) < 111) ? amp * Wv[(T)] : 0.0f;                        \
    if (act) {                                                                  \
        float4 hu2 = LD4(Ps, pc0 - 2 * SROW);                                   \
        float4 hu1 = LD4(Ps, pc0 - 1 * SROW);                                   \
        float4 hd1, hd2;                                                        \
        _Pragma("unroll")                                                       \
        for (int r = 0; r < RH; ++r) {                                          \
            if (r < zlim) {                                                     \
                if (r == RH - 2) {                                              \
                    hd1 = LD4(Ps, pc0 + RH * SROW);                             \
                    hd2 = LD4(Ps, pc0 + (RH + 1) * SROW);                       \
                }                                                               \
                const int pc = pc0 + r * SROW;                                  \
                float2 hl = LD2(Ps, pc - 2);                                    \
                float2 hr = LD2(Ps, pc + 4);                                    \
                float4 c  = CUR[r];                                             \
                float4 u1 = (r == 0) ? hu1 : CUR[(r >= 1) ? r - 1 : 0];         \
                float4 u2 = (r == 0) ? hu2 :                                    \
                            ((r == 1) ? hu1 : CUR[(r >= 2) ? r - 2 : 0]);       \
                float4 d1 = (r == RH - 1) ? hd1 : CUR[(r + 1 < RH) ? r + 1 : 0];\
                float4 d2 = (r == RH - 1) ? hd2 :                               \
                            ((r == RH - 2) ? hd1 : CUR[(r + 2 < RH) ? r + 2 : 0]);\
                float4 al = AL4[cb0 + r * 40];                                  \
                float4 kd = KD4[cb0 + r * 40];                                  \
                float4 p0 = OLD[r];                                             \
                float4 q;                                                       \
                q.x = cellq(hl.x, hl.y, c.x, c.y, c.z,                          \
                            u1.x, u2.x, d1.x, d2.x, al.x, kd.x, p0.x);          \
                q.y = cellq(hl.y, c.x, c.y, c.z, c.w,                           \
                            u1.y, u2.y, d1.y, d2.y, al.y, kd.y, p0.y);          \
                q.z = cellq(c.x, c.y, c.z, c.w, hr.x,                           \
                            u1.z, u2.z, d1.z, d2.z, al.z, kd.z, p0.z);          \
                q.w = cellq(c.y, c.z, c.w, hr.x, hr.y,                          \
                            u1.w, u2.w, d1.w, d2.w, al.w, kd.w, p0.w);          \
                if (r == 9 && isrc) {   /* source z=31 = (g=2, r=9), post-stencil */ \
                    q.x += (ls == 0) ? as : 0.0f;                               \
                    q.y += (ls == 1) ? as : 0.0f;                               \
                    q.z += (ls == 2) ? as : 0.0f;                               \
                    q.w += (ls == 3) ? as : 0.0f;                               \
                }                                                               \
                OLD[r] = q;             /* new gen overwrites old gen */        \
            }                                                                   \
        }                                                                       \
    }                                                                           \
    __syncthreads();                    /* all halo reads of Ps complete */     \
    if (act) {                                                                  \
        _Pragma("unroll")                                                       \
        for (int r = 0; r < RH; ++r)                                            \
            if (r < zlim) ST4(Ps, pc0 + r * SROW, OLD[r]);                      \
    }                                                                           \
    __syncthreads();                    /* new p1 visible */                    \
    if (tid < 100)                      /* receivers: z=31, x=30..129 */        \
        out[shot * 100000 + (T) * 100 + tid] = Ps[33 * SROW + 34 + tid];        \
} while (0)

// ---------- main: one block per shot, 1000 steps ----------
__global__ __launch_bounds__(512) void fwi_main(const float4* __restrict__ AL4,
                                                const float4* __restrict__ KD4,
                                                const float* __restrict__ ws,
                                                float* __restrict__ out) {
    __shared__ float Ps[PSZ];      // p1 mirror, haloed, stride 168 (91,392 B)
    __shared__ float Wv[128];      // Ricker wavelet (nonzero only t < 111)
    const int tid = threadIdx.x;
    const int shot = blockIdx.x;

    for (int i = tid; i < PSZ; i += 512) Ps[i] = 0.0f;
    if (tid < 128) Wv[tid] = (tid < 111) ? ws[tid] : 0.0f;

    const int g  = tid / 40;            // z-group 0..11 active, >=12 idle
    const int qx = tid - g * 40;        // x-quad 0..39, cells x0 = 4*qx
    const int z0 = g * RH;
    const bool act = (g < NGRP);
    const float amp = ws[1000 + shot];
    const int xs = 30 + 11 * shot;      // source x (z=31 -> g=2, r=9)
    const bool isrc = act && (g == 2) && (qx == (xs >> 2));
    const int ls = xs & 3;
    const int pc0 = (z0 + 2) * SROW + 4 * qx + 4;  // Ps index of row z0 quad
    const int cb0 = z0 * 40 + qx;                  // coefficient quad index
    const int zlim = 130 - z0;                     // rows r < zlim are valid (g11: 9)

    float4 pA[RH], pB[RH];              // two field generations, all in regs
    #pragma unroll
    for (int r = 0; r < RH; ++r) {
        pA[r] = make_float4(0.f, 0.f, 0.f, 0.f);
        pB[r] = make_float4(0.f, 0.f, 0.f, 0.f);
    }
    __syncthreads();

    for (int t = 0; t < 1000; t += 2) {
        STEP(pB, pA, t);       // p1=pB, p0=pA -> new field lands in pA
        STEP(pA, pB, t + 1);   // roles swapped; static register names
    }
}

extern "C" void kernel_launch(void* const* d_in, const int* in_sizes, int n_in,
                              void* d_out, int out_size, void* d_ws, size_t ws_size,
                              hipStream_t stream) {
    const float* v = (const float*)d_in[0];
    float* ws = (float*)d_ws;                          // [0..999] wavelet, [1000..1009] amps, [1010] velmin
    float* AL = (float*)((char*)d_ws + 4096);          // 20800 floats
    float* KD = (float*)((char*)d_ws + 4096 + 83200);  // 20800 floats
    float* out = (float*)d_out;

    fwi_setup1<<<1, 1024, 0, stream>>>(v, ws);
    fwi_setup2<<<82, 256, 0, stream>>>(v, ws, AL, KD);
    fwi_main<<<10, 512, 0, stream>>>((const float4*)AL, (const float4*)KD, ws, out);
}

// Round 9
// 3092.328 us; speedup vs baseline: 2.6410x; 1.3946x over previous
//
#include <hip/hip_runtime.h>
#include <math.h>

// FWI forward: 10 shots, 1000 steps, padded grid 130x160 (NBC=30).
// R9 = R8 with the zlim bug fixed: R8 used zlim = 130 - z0 (=130,119,...,20,9)
// so the q-lag tail's `if (zlim == 11)` was NEVER true; groups g<11 clobbered
// pA[7..8] with q[9..10] and left pA[9..10] stale -> absmax 45. Fix:
// zlim = min(130 - z0, RH) -> {11 for g<11, 9 for g==11}.
//
// Design (R8): fixed-role in-place update. pA regs hold p1 and morph into
// p_new via a 2-row q-lag (pA[r-2] <- q[r-2] after rows r-1,r consumed it as
// their z-neighbor) -> no 44-reg pn carry (R7's budget killer). p0: rows 0..6
// in per-thread LDS (stride 28 words, 16B-aligned, uniform banks), rows 7..10
// in 16 regs. Coefficients AL,T1 captured-then-prefetched 2 rows ahead.
// t2 = t1 + 5*al - 1 (R4-validated rounding). Persistent state ~75 regs.

#define SROW 168                 // Ps row stride; col = x + 4
#define PSZ (136 * SROW)         // stored rows -2..133
#define RH 11                    // rows per thread
#define DTf 0.0008f
#define C2f 1.3333333333333333f  // 4/3
#define C3f (-0.08333333333333333f) // -1/12

#define LD4(arr, i) (*reinterpret_cast<const float4*>(&(arr)[i]))
#define LD2(arr, i) (*reinterpret_cast<const float2*>(&(arr)[i]))
#define ST4(arr, i, v) (*reinterpret_cast<float4*>(&(arr)[i]) = (v))

// ---------- setup 1: velmin reduction, Ricker wavelet, source amplitudes ----------
__global__ __launch_bounds__(1024) void fwi_setup1(const float* __restrict__ v,
                                                   float* __restrict__ ws) {
    int tid = threadIdx.x;
    float m = 3.402823466e38f;
    for (int i = tid; i < 7000; i += 1024) m = fminf(m, v[i]);
    #pragma unroll
    for (int off = 32; off > 0; off >>= 1) m = fminf(m, __shfl_down(m, off, 64));
    __shared__ float red[16];
    if ((tid & 63) == 0) red[tid >> 6] = m;
    __syncthreads();
    if (tid == 0) {
        float mm = red[0];
        for (int i = 1; i < 16; ++i) mm = fminf(mm, red[i]);
        ws[1010] = mm * 1000.0f + 3000.0f;   // denormalized velmin
    }
    // Ricker wavelet: nw=111, nc=55, f*dt*pi = 0.06283185307179587
    if (tid < 1000) {
        float w = 0.0f;
        if (tid < 111) {
            float a = (float)(55 - tid) * 0.06283185307179587f;
            float b = a * a;
            w = (1.0f - 2.0f * b) * expf(-b);
        }
        ws[tid] = w;
    }
    // src_amp[l] = ((v[1][11l]*1000+3000)*DT)^2
    if (tid >= 1000 && tid < 1010) {
        int l = tid - 1000;
        float vd = v[100 + 11 * l] * 1000.0f + 3000.0f;
        float bdt = vd * DTf;
        ws[tid] = bdt * bdt;
    }
}

// ---------- setup 2: per-cell constants AL (alpha), T1 (temp1); 132-row padded ----------
__global__ __launch_bounds__(256) void fwi_setup2(const float* __restrict__ v,
                                                  const float* __restrict__ ws,
                                                  float* __restrict__ AL,
                                                  float* __restrict__ T1) {
    int c = blockIdx.x * 256 + threadIdx.x;
    if (c >= 132 * 160) return;
    if (c >= 130 * 160) { AL[c] = 0.0f; T1[c] = 0.0f; return; }  // prefetch pad
    float velmin = ws[1010];
    int z = c / 160;
    int x = c - z * 160;
    int iz = min(max(z - 30, 0), 69);
    int ix = min(max(x - 30, 0), 99);
    float vd = v[iz * 100 + ix] * 1000.0f + 3000.0f;
    float tt = vd * DTf / 10.0f;       // v*DT/DX
    float al = tt * tt;                // alpha
    int qx = max(29 - x, x - 130);
    int qz = max(29 - z, z - 100);
    int q = (qx >= 0) ? qx : qz;
    float kdt = 0.0f;
    if (q >= 0) {
        float kap3 = 3.0f * velmin * 16.118095650958319f / 580.0f; // 3*velmin*ln(1e7)/(2*290)
        float r = (float)q * (10.0f / 290.0f);
        kdt = kap3 * (r * r) * DTf;
    }
    AL[c] = al;
    T1[c] = 2.0f - 5.0f * al - kdt;    // temp1; temp2 = t1 + 5*al - 1 (R4-validated)
}

__device__ __forceinline__ float cellq(float l2, float l1, float cc, float r1, float r2,
                                       float u1, float u2, float d1, float d2,
                                       float al, float t1, float p0) {
    float lap = C2f * ((l1 + r1) + (u1 + d1)) + C3f * ((l2 + r2) + (u2 + d2));
    float t2  = t1 + 5.0f * al - 1.0f;           // temp2 = 1 - kdt (R4 rounding)
    return t1 * cc - t2 * p0 + al * lap;
}

// ---------- main: one block per shot, 1000 steps ----------
__global__ __launch_bounds__(512) void fwi_main(const float4* __restrict__ AL4,
                                                const float4* __restrict__ T14,
                                                const float* __restrict__ ws,
                                                float* __restrict__ out) {
    __shared__ float Ps[PSZ];          // p1 mirror, haloed (91,392 B)
    __shared__ float P0s[512 * 28];    // p0 rows 0..6, per-thread stride 28 (57,344 B)
    __shared__ float Wv[128];          // Ricker wavelet (nonzero only t < 111)
    const int tid = threadIdx.x;
    const int shot = blockIdx.x;

    for (int i = tid; i < PSZ; i += 512) Ps[i] = 0.0f;
    for (int i = tid; i < 512 * 28; i += 512) P0s[i] = 0.0f;
    if (tid < 128) Wv[tid] = (tid < 111) ? ws[tid] : 0.0f;

    const int g  = tid / 40;            // z-group 0..11 active, >=12 idle
    const int qx = tid - g * 40;        // x-quad 0..39, cells x0 = 4*qx
    const int z0 = g * RH;
    const bool act = (g < 12);
    const float amp = ws[1000 + shot];
    const int xs = 30 + 11 * shot;      // source x (z=31 -> g=2, r=9)
    const bool isrc = act && (g == 2) && (qx == (xs >> 2));
    const int ls = xs & 3;
    const int pc0 = (z0 + 2) * SROW + 4 * qx + 4;  // Ps index of row z0 quad
    const int cb0 = z0 * 40 + qx;                  // coefficient quad index
    const int p0b = tid * 28;                      // P0s per-thread base (words)
    const int zlim = min(130 - z0, RH);            // g<11: 11, g==11: 9  (R8 BUG FIX)

    float4 pA[RH];                      // p1, morphs into p_new via q-lag
    float4 p0r[4];                      // p0 rows 7..10
    #pragma unroll
    for (int r = 0; r < RH; ++r) pA[r] = make_float4(0.f, 0.f, 0.f, 0.f);
    #pragma unroll
    for (int r = 0; r < 4; ++r) p0r[r] = make_float4(0.f, 0.f, 0.f, 0.f);
    __syncthreads();

    for (int t = 0; t < 1000; ++t) {
        const float as = (t < 111) ? amp * Wv[t] : 0.0f;

        // ---- phase A: in-place stencil with 2-row q-lag ----
        if (act) {
            float4 ae = AL4[cb0], te = T14[cb0];               // row 0 coefs
            float4 ao = AL4[cb0 + 40], to_ = T14[cb0 + 40];    // row 1 coefs
            float4 hu2 = LD4(Ps, pc0 - 2 * SROW);
            float4 hu1 = LD4(Ps, pc0 - 1 * SROW);
            float4 hd1 = make_float4(0.f, 0.f, 0.f, 0.f);
            float4 hd2 = make_float4(0.f, 0.f, 0.f, 0.f);
            float4 qm2 = make_float4(0.f, 0.f, 0.f, 0.f);
            float4 qm1 = make_float4(0.f, 0.f, 0.f, 0.f);
            #pragma unroll
            for (int r = 0; r < RH; ++r) {
                if (r < zlim) {
                    // capture THIS row's coefs from the parity slot...
                    float4 al = (r & 1) ? ao : ae;
                    float4 t1 = (r & 1) ? to_ : te;
                    // ...then prefetch row r+2 into that (same-parity) slot
                    if (r < RH - 2) {
                        if (r & 1) { ao = AL4[cb0 + (r + 2) * 40];
                                     to_ = T14[cb0 + (r + 2) * 40]; }
                        else       { ae = AL4[cb0 + (r + 2) * 40];
                                     te = T14[cb0 + (r + 2) * 40]; }
                    }
                    if (r == 8) {                       // z-halo below, 1-row lead
                        hd1 = LD4(Ps, pc0 + RH * SROW);
                        hd2 = LD4(Ps, pc0 + (RH + 1) * SROW);
                    }
                    const int pc = pc0 + r * SROW;
                    float2 hl = LD2(Ps, pc - 2);
                    float2 hr = LD2(Ps, pc + 4);
                    float4 c  = pA[r];
                    float4 u1 = (r == 0) ? hu1 : pA[(r >= 1) ? r - 1 : 0];
                    float4 u2 = (r == 0) ? hu2 :
                                ((r == 1) ? hu1 : pA[(r >= 2) ? r - 2 : 0]);
                    float4 d1 = (r == RH - 1) ? hd1 : pA[(r + 1 < RH) ? r + 1 : 0];
                    float4 d2 = (r == RH - 1) ? hd2 :
                                ((r == RH - 2) ? hd1 : pA[(r + 2 < RH) ? r + 2 : 0]);
                    float4 p0 = (r < 7) ? LD4(P0s, p0b + 4 * r)
                                        : p0r[(r >= 7) ? r - 7 : 0];
                    float4 q;
                    q.x = cellq(hl.x, hl.y, c.x, c.y, c.z,
                                u1.x, u2.x, d1.x, d2.x, al.x, t1.x, p0.x);
                    q.y = cellq(hl.y, c.x, c.y, c.z, c.w,
                                u1.y, u2.y, d1.y, d2.y, al.y, t1.y, p0.y);
                    q.z = cellq(c.x, c.y, c.z, c.w, hr.x,
                                u1.z, u2.z, d1.z, d2.z, al.z, t1.z, p0.z);
                    q.w = cellq(c.y, c.z, c.w, hr.x, hr.y,
                                u1.w, u2.w, d1.w, d2.w, al.w, t1.w, p0.w);
                    if (r == 9 && isrc) {               // source injection (z=31)
                        q.x += (ls == 0) ? as : 0.0f;
                        q.y += (ls == 1) ? as : 0.0f;
                        q.z += (ls == 2) ? as : 0.0f;
                        q.w += (ls == 3) ? as : 0.0f;
                    }
                    // p0 <- old p1 center (owner-private)
                    if (r < 7) ST4(P0s, p0b + 4 * r, c);
                    else       p0r[(r >= 7) ? r - 7 : 0] = c;
                    // q-lag commit: rows r-1, r have consumed old pA[r-2]
                    if (r >= 2) pA[(r >= 2) ? r - 2 : 0] = qm2;
                    qm2 = qm1;
                    qm1 = q;
                }
            }
            // tail: commit the last two rows (zlim is 11 or 9, static per branch)
            if (zlim == 11) { pA[9] = qm2; pA[10] = qm1; }
            else            { pA[7] = qm2; pA[8] = qm1; }   // g == 11 (zlim 9)
        }
        __syncthreads();               // all Ps reads complete

        // ---- phase B: commit p_new (now in pA) to Ps ----
        if (act) {
            #pragma unroll
            for (int r = 0; r < RH; ++r)
                if (r < zlim) ST4(Ps, pc0 + r * SROW, pA[r]);
        }
        __syncthreads();               // new p1 visible

        // ---- phase C: receivers z=31, x=30..129 ----
        if (tid < 100) out[shot * 100000 + t * 100 + tid] = Ps[33 * SROW + 34 + tid];
    }
}

extern "C" void kernel_launch(void* const* d_in, const int* in_sizes, int n_in,
                              void* d_out, int out_size, void* d_ws, size_t ws_size,
                              hipStream_t stream) {
    const float* v = (const float*)d_in[0];
    float* ws = (float*)d_ws;                          // [0..999] wavelet, [1000..1009] amps, [1010] velmin
    float* AL = (float*)((char*)d_ws + 4096);          // 21120 floats (132 rows)
    float* T1 = (float*)((char*)d_ws + 4096 + 84480);  // 21120 floats
    float* out = (float*)d_out;

    fwi_setup1<<<1, 1024, 0, stream>>>(v, ws);
    fwi_setup2<<<83, 256, 0, stream>>>(v, ws, AL, T1);
    fwi_main<<<10, 512, 0, stream>>>((const float4*)AL, (const float4*)T1, ws, out);
}